// Round 1
// 1221.471 us; speedup vs baseline: 1.1742x; 1.1742x over previous
//
#include <hip/hip_runtime.h>
#include <cstdint>
#include <cstddef>

typedef _Float16 f16x8 __attribute__((ext_vector_type(8)));
typedef _Float16 f16x4 __attribute__((ext_vector_type(4)));
typedef float    f32x4 __attribute__((ext_vector_type(4)));

#define TFR  11
#define HID  1024
#define DQK  256
#define NBATCH 8192
#define MROWS (NBATCH*TFR)   /* 90112 */
#define NCAT 1536            /* Q(256) cat K(256) cat HV(1024) */

// ws layout (bytes). Total ~284.2 MB (same footprint as previous version).
#define OFF_QKHV ((size_t)0)                        // [90112,1536] f16
#define OFF_WCAT ((size_t)276824064)                // [1536,1024] f16 (Wqk ; Wov)
#define OFF_WVT  ((size_t)279969792)                // [1024,1024] f16 (Wv^T)
#define OFF_WO   ((size_t)282066944)                // [1024,1024] f16
#define OFF_BCAT ((size_t)284164096)                // [1536] f32 (bqk ; zeros)
#define OFF_BF   ((size_t)284170240)                // [1024] f32 (Wo@bv + bo)
#define OFF_TAB  ((size_t)284174336)                // [121] f32

static __device__ __forceinline__ void gl2lds16(const void* g, void* l) {
  __builtin_amdgcn_global_load_lds(
      (const __attribute__((address_space(1))) void*)g,
      (__attribute__((address_space(3))) void*)l, 16, 0, 0);
}

// ---------------------------------------------------------------------------
// weight prep: Wqk cat+cvt into wcat rows 0..511, Wo cvt, Wv transpose+cvt,
// bcat (bqk ; zeros), coulomb table.  grid 1280 x 256 = 327680 indices.
// ---------------------------------------------------------------------------
__global__ __launch_bounds__(256)
void prep_w(const float* __restrict__ Wq, const float* __restrict__ Wk,
            const float* __restrict__ Wv, const float* __restrict__ Wo,
            const float* __restrict__ bq, const float* __restrict__ bk,
            const float* __restrict__ screen_d, const float* __restrict__ scale,
            _Float16* __restrict__ wcat, _Float16* __restrict__ wo16,
            _Float16* __restrict__ wvt, float* __restrict__ bcat,
            float* __restrict__ tab)
{
  const int idx = blockIdx.x * 256 + threadIdx.x;
  if (idx < 65536) {                       // Wqk -> wcat rows 0..511
    const int n = idx >> 7, c = (idx & 127) * 8;
    const float* src = (n < 256) ? &Wq[(size_t)n * 1024 + c]
                                 : &Wk[(size_t)(n - 256) * 1024 + c];
    f32x4 a = *(const f32x4*)src, b = *(const f32x4*)(src + 4);
    f16x8 o;
    o[0]=(_Float16)a[0]; o[1]=(_Float16)a[1]; o[2]=(_Float16)a[2]; o[3]=(_Float16)a[3];
    o[4]=(_Float16)b[0]; o[5]=(_Float16)b[1]; o[6]=(_Float16)b[2]; o[7]=(_Float16)b[3];
    *(f16x8*)&wcat[(size_t)n * 1024 + c] = o;
  } else if (idx < 196608) {               // Wo cvt
    const size_t e = (size_t)(idx - 65536) * 8;
    f32x4 a = *(const f32x4*)&Wo[e], b = *(const f32x4*)&Wo[e + 4];
    f16x8 o;
    o[0]=(_Float16)a[0]; o[1]=(_Float16)a[1]; o[2]=(_Float16)a[2]; o[3]=(_Float16)a[3];
    o[4]=(_Float16)b[0]; o[5]=(_Float16)b[1]; o[6]=(_Float16)b[2]; o[7]=(_Float16)b[3];
    *(f16x8*)&wo16[e] = o;
  } else if (idx < 327680) {               // WvT[n,k] = Wv[k,n]
    const int j = idx - 196608;
    const int n = j & 1023, kc = j >> 10;  // kc: 0..127
    f16x8 o;
#pragma unroll
    for (int e = 0; e < 8; ++e)
      o[e] = (_Float16)Wv[(size_t)(kc * 8 + e) * 1024 + n];
    *(f16x8*)&wvt[(size_t)n * 1024 + kc * 8] = o;
  }
  if (idx < NCAT)
    bcat[idx] = (idx < 256) ? bq[idx] : (idx < 512) ? bk[idx - 256] : 0.0f;
  if (idx < TFR * TFR) {
    const int i = idx / TFR, j = idx % TFR;
    const float r = fabsf((float)(i - j));
    float acc = 0.f, sign = 1.f;
    for (int k = 0; k < 3; ++k) {
      const float d = screen_d[k];
      acc += sign * rsqrtf(d * d + r * r + 1e-6f);
      sign = -sign;
    }
    tab[idx] = acc / (scale[0] + 1e-6f);
  }
}

// bfused[o] = sum_m Wo[o,m]*bv[m] + bo[o].  grid 1024 x 64 (one wave/row).
__global__ __launch_bounds__(64)
void bfused_k(const float* __restrict__ Wo, const float* __restrict__ bv,
              const float* __restrict__ bo, float* __restrict__ bf)
{
  const int o = blockIdx.x, l = threadIdx.x;
  float acc = 0.f;
  for (int m = l; m < 1024; m += 64) acc += Wo[(size_t)o * 1024 + m] * bv[m];
#pragma unroll
  for (int off = 32; off >= 1; off >>= 1) acc += __shfl_xor(acc, off);
  if (l == 0) bf[o] = acc + bo[o];
}

// ---------------------------------------------------------------------------
// f16 MFMA GEMM (m97 structure): out[m,n] = sum_k A[m,k]*B[n,k] (+bias[n]).
// AF32=1: A is f32, reg-staged + converted to f16 on the way to LDS.
// SWZ=1: bijective XCD swizzle for grid (12,704) (8448 % 8 == 0).
// 128x128 tile, BK=32, 256 thr (2x2 waves of 64x64), 16x16x32 f16 MFMA.
// ---------------------------------------------------------------------------
struct __align__(16) GemmSmem {
  union {
    struct { _Float16 A[128 * 32]; _Float16 B[128 * 32]; } st;  // 16 KB
    _Float16 E16[128 * 136];   // 34816 B (epilogue)
  };
};

template <int AF32, int SWZ>
__global__ __launch_bounds__(256)
void gemm_f16(const void* __restrict__ Av, int lda,
              const _Float16* __restrict__ B,
              const float* __restrict__ bias,
              _Float16* __restrict__ out, int ldo, int K)
{
  __shared__ GemmSmem sm;
  const int t = threadIdx.x;
  int bx, by;
  if constexpr (SWZ) {
    // grid (12,704): 8448 wgs, 8448/8 = 1056 per XCD chunk.
    const int orig = blockIdx.y * 12 + blockIdx.x;
    const int wg = (orig & 7) * 1056 + (orig >> 3);
    bx = wg % 12; by = wg / 12;
  } else {
    bx = blockIdx.x; by = blockIdx.y;
  }
  const int n0 = bx * 128;
  const int m0 = by * 128;
  const int w  = t >> 6, l = t & 63;
  const int wm = (w & 1) * 64, wn = (w >> 1) * 64;
  const int lr = l & 15, lg = l >> 4;

  f32x4 acc[4][4] = {};

  const int qa = t, qb = t + 256;   // 16B chunk ids: row q>>2, sub-chunk q&3
  _Float16* ldsA0 = &sm.st.A[qa * 8];
  _Float16* ldsA1 = &sm.st.A[qb * 8];
  _Float16* ldsB0 = &sm.st.B[qa * 8];
  _Float16* ldsB1 = &sm.st.B[qb * 8];
  const _Float16* Brow0 = B + (size_t)(n0 + (qa >> 2)) * K + (qa & 3) * 8;
  const _Float16* Brow1 = B + (size_t)(n0 + (qb >> 2)) * K + (qb & 3) * 8;
  const float*    A32r0 = (const float*)Av    + (size_t)(m0 + (qa >> 2)) * lda + (qa & 3) * 8;
  const float*    A32r1 = (const float*)Av    + (size_t)(m0 + (qb >> 2)) * lda + (qb & 3) * 8;
  const _Float16* A16r0 = (const _Float16*)Av + (size_t)(m0 + (qa >> 2)) * lda + (qa & 3) * 8;
  const _Float16* A16r1 = (const _Float16*)Av + (size_t)(m0 + (qb >> 2)) * lda + (qb & 3) * 8;

  for (int kt = 0; kt < K; kt += 32) {
    if constexpr (AF32) {
      // B via async DMA first, then A reg-stage (f32 -> f16) overlaps it.
      gl2lds16(Brow0 + kt, ldsB0);
      gl2lds16(Brow1 + kt, ldsB1);
      f32x4 x0 = *(const f32x4*)(A32r0 + kt);
      f32x4 x1 = *(const f32x4*)(A32r0 + kt + 4);
      f32x4 y0 = *(const f32x4*)(A32r1 + kt);
      f32x4 y1 = *(const f32x4*)(A32r1 + kt + 4);
      f16x8 o0, o1;
#pragma unroll
      for (int e = 0; e < 4; ++e) {
        o0[e] = (_Float16)x0[e]; o0[4 + e] = (_Float16)x1[e];
        o1[e] = (_Float16)y0[e]; o1[4 + e] = (_Float16)y1[e];
      }
      *(f16x8*)ldsA0 = o0;
      *(f16x8*)ldsA1 = o1;
    } else {
      gl2lds16(A16r0 + kt, ldsA0);
      gl2lds16(A16r1 + kt, ldsA1);
      gl2lds16(Brow0 + kt, ldsB0);
      gl2lds16(Brow1 + kt, ldsB1);
    }
    __syncthreads();

    f16x8 af[4], bf[4];
#pragma unroll
    for (int mi = 0; mi < 4; ++mi)
      af[mi] = *(const f16x8*)&sm.st.A[(wm + mi * 16 + lr) * 32 + lg * 8];
#pragma unroll
    for (int ni = 0; ni < 4; ++ni)
      bf[ni] = *(const f16x8*)&sm.st.B[(wn + ni * 16 + lr) * 32 + lg * 8];
#pragma unroll
    for (int mi = 0; mi < 4; ++mi)
#pragma unroll
      for (int ni = 0; ni < 4; ++ni)
        acc[mi][ni] = __builtin_amdgcn_mfma_f32_16x16x32_f16(af[mi], bf[ni], acc[mi][ni], 0, 0, 0);
    __syncthreads();
  }

  // f16 epilogue (+bias)
  float bias4[4];
#pragma unroll
  for (int ni = 0; ni < 4; ++ni)
    bias4[ni] = bias ? bias[n0 + wn + ni * 16 + lr] : 0.0f;
#pragma unroll
  for (int mi = 0; mi < 4; ++mi)
#pragma unroll
    for (int ni = 0; ni < 4; ++ni) {
      const int row = wm + mi * 16 + lg * 4;   // C/D: col=lane&15, row=(lane>>4)*4+reg
      const int col = wn + ni * 16 + lr;
#pragma unroll
      for (int r = 0; r < 4; ++r)
        sm.E16[(row + r) * 136 + col] = (_Float16)(acc[mi][ni][r] + bias4[ni]);
    }
  __syncthreads();
#pragma unroll
  for (int i = 0; i < 8; ++i) {
    const int q = t + i * 256;               // row q>>4, col chunk q&15
    const int row = q >> 4, c = (q & 15) * 8;
    *(f16x8*)&out[(size_t)(m0 + row) * ldo + n0 + c] = *(const f16x8*)&sm.E16[row * 136 + c];
  }
}

// ---------------------------------------------------------------------------
// fold + LN: per batch, scores = Q K^T/16 + coulomb, softmax -> P,
// x = P @ hv + bfused + h, out = LayerNorm(x).  One block per batch.
// qkhv row: [Q(0..255) | K(256..511) | hv(512..1535)]
// ---------------------------------------------------------------------------
__global__ __launch_bounds__(256)
void fold_ln(const _Float16* __restrict__ qkhv, const float* __restrict__ h,
             const float* __restrict__ bfused, const float* __restrict__ tab,
             const float* __restrict__ gamma, const float* __restrict__ beta,
             float* __restrict__ out)
{
  __shared__ __align__(16) _Float16 sQH[TFR * NCAT];   // 33792 B
  __shared__ float sSc[TFR][12];
  __shared__ float sP[TFR][12];
  __shared__ float sRed[TFR][8];
  const int t = threadIdx.x;
  const size_t qbase = (size_t)blockIdx.x * (TFR * NCAT);

  for (int q = t; q < TFR * NCAT / 8; q += 256)
    *(f16x8*)&sQH[q * 8] = *(const f16x8*)&qkhv[qbase + (size_t)q * 8];
  __syncthreads();

  if (t < TFR * TFR) {
    const int i = t / TFR, j = t % TFR;
    float acc = 0.f;
    for (int c = 0; c < DQK; c += 8) {
      f16x8 qv = *(const f16x8*)&sQH[i * NCAT + c];
      f16x8 kv = *(const f16x8*)&sQH[j * NCAT + DQK + c];
#pragma unroll
      for (int e = 0; e < 8; ++e) acc += (float)qv[e] * (float)kv[e];
    }
    sSc[i][j] = acc * 0.0625f + tab[t];   // 1/sqrt(256)
  }
  __syncthreads();

  if (t < TFR) {
    float mx = sSc[t][0];
    for (int j = 1; j < TFR; ++j) mx = fmaxf(mx, sSc[t][j]);
    float e[TFR], sum = 0.f;
    for (int j = 0; j < TFR; ++j) { e[j] = __expf(sSc[t][j] - mx); sum += e[j]; }
    const float inv = 1.f / sum;
    for (int j = 0; j < TFR; ++j) sP[t][j] = e[j] * inv;
  }
  __syncthreads();

  const int c = t * 4;
  const int w = t >> 6, l = t & 63;
  const f32x4 bfv = *(const f32x4*)&bfused[c];
  const size_t hbase = (size_t)blockIdx.x * (TFR * HID);
  f32x4 acc[TFR];
#pragma unroll
  for (int i = 0; i < TFR; ++i) {
    f32x4 a = {};
#pragma unroll
    for (int j = 0; j < TFR; ++j) {
      const float p = sP[i][j];
      const f16x4 hv = *(const f16x4*)&sQH[j * NCAT + 512 + c];
      a[0] += p * (float)hv[0]; a[1] += p * (float)hv[1];
      a[2] += p * (float)hv[2]; a[3] += p * (float)hv[3];
    }
    const f32x4 rv = *(const f32x4*)&h[hbase + (size_t)i * HID + c];
#pragma unroll
    for (int e = 0; e < 4; ++e) a[e] += bfv[e] + rv[e];
    acc[i] = a;
    float s  = a[0] + a[1] + a[2] + a[3];
    float s2 = a[0]*a[0] + a[1]*a[1] + a[2]*a[2] + a[3]*a[3];
#pragma unroll
    for (int off = 32; off >= 1; off >>= 1) {
      s  += __shfl_xor(s, off);
      s2 += __shfl_xor(s2, off);
    }
    if (l == 0) { sRed[i][w] = s; sRed[i][w + 4] = s2; }
  }
  __syncthreads();

  const f32x4 gv = *(const f32x4*)&gamma[c];
  const f32x4 bv = *(const f32x4*)&beta[c];
#pragma unroll
  for (int i = 0; i < TFR; ++i) {
    const float s  = sRed[i][0] + sRed[i][1] + sRed[i][2] + sRed[i][3];
    const float s2 = sRed[i][4] + sRed[i][5] + sRed[i][6] + sRed[i][7];
    const float mu  = s * (1.f / HID);
    const float var = s2 * (1.f / HID) - mu * mu;
    const float rs  = rsqrtf(var + 1e-5f);
    const f32x4 a = acc[i];
    f32x4 o;
#pragma unroll
    for (int e = 0; e < 4; ++e) o[e] = (a[e] - mu) * rs * gv[e] + bv[e];
    *(f32x4*)&out[hbase + (size_t)i * HID + c] = o;
  }
}

// ---------------------------------------------------------------------------
extern "C" void kernel_launch(void* const* d_in, const int* in_sizes, int n_in,
                              void* d_out, int out_size, void* d_ws, size_t ws_size,
                              hipStream_t stream)
{
  const float* h     = (const float*)d_in[0];
  const float* Wq    = (const float*)d_in[1];
  const float* bq    = (const float*)d_in[2];
  const float* Wk    = (const float*)d_in[3];
  const float* bk    = (const float*)d_in[4];
  const float* Wv    = (const float*)d_in[5];
  const float* bv    = (const float*)d_in[6];
  const float* Wo    = (const float*)d_in[7];
  const float* bo    = (const float*)d_in[8];
  const float* gamma = (const float*)d_in[9];
  const float* beta  = (const float*)d_in[10];
  const float* sd    = (const float*)d_in[11];
  const float* scal  = (const float*)d_in[12];
  float* out = (float*)d_out;

  char* w = (char*)d_ws;
  _Float16* qkhv = (_Float16*)(w + OFF_QKHV);
  _Float16* wcat = (_Float16*)(w + OFF_WCAT);
  _Float16* wvt  = (_Float16*)(w + OFF_WVT);
  _Float16* wo16 = (_Float16*)(w + OFF_WO);
  float* bcat    = (float*)(w + OFF_BCAT);
  float* bfused  = (float*)(w + OFF_BF);
  float* tab     = (float*)(w + OFF_TAB);

  prep_w<<<1280, 256, 0, stream>>>(Wq, Wk, Wv, Wo, bq, bk, sd, scal,
                                   wcat, wo16, wvt, bcat, tab);
  bfused_k<<<1024, 64, 0, stream>>>(Wo, bv, bo, bfused);

  // Wov = Wo @ Wv -> wcat rows 512..1535: out[o,k] = sum_j Wo[o,j] * WvT[k,j]
  gemm_f16<0, 0><<<dim3(8, 8), 256, 0, stream>>>(
      wo16, 1024, wvt, nullptr, wcat + (size_t)512 * 1024, 1024, 1024);

  // qkhv = h @ [Wqk ; Wov]^T + [bqk ; 0]   (A = f32 h, reg-staged)
  gemm_f16<1, 1><<<dim3(12, 704), 256, 0, stream>>>(
      h, 1024, wcat, bcat, qkhv, NCAT, 1024);

  // scores/softmax/PV + bfused + residual + LayerNorm, fused per batch
  fold_ln<<<NBATCH, 256, 0, stream>>>(qkhv, h, bfused, tab, gamma, beta, out);
}

// Round 2
// 1099.892 us; speedup vs baseline: 1.3040x; 1.1105x over previous
//
#include <hip/hip_runtime.h>
#include <cstdint>
#include <cstddef>

typedef _Float16 f16x8 __attribute__((ext_vector_type(8)));
typedef _Float16 f16x4 __attribute__((ext_vector_type(4)));
typedef float    f32x4 __attribute__((ext_vector_type(4)));

#define TFR  11
#define HID  1024
#define DQK  256
#define NBATCH 8192
#define MROWS (NBATCH*TFR)   /* 90112 */
#define NCAT 1536            /* Q(256) cat K(256) cat HV(1024) */

// ws layout (bytes). Total ~284.2 MB.
// NOTE: f16 copy of h lives in d_out (369 MB f32 out buffer, dead until fold_ln).
#define OFF_QKHV ((size_t)0)                        // [90112,1536] f16
#define OFF_WCAT ((size_t)276824064)                // [1536,1024] f16 (Wqk ; Wov)
#define OFF_WVT  ((size_t)279969792)                // [1024,1024] f16 (Wv^T)
#define OFF_WO   ((size_t)282066944)                // [1024,1024] f16
#define OFF_BCAT ((size_t)284164096)                // [1536] f32 (bqk ; zeros)
#define OFF_BF   ((size_t)284170240)                // [1024] f32 (Wo@bv + bo)
#define OFF_TAB  ((size_t)284174336)                // [121] f32

static __device__ __forceinline__ void gl2lds16(const void* g, void* l) {
  __builtin_amdgcn_global_load_lds(
      (const __attribute__((address_space(1))) void*)g,
      (__attribute__((address_space(3))) void*)l, 16, 0, 0);
}

// ---------------------------------------------------------------------------
// h (f32) -> f16 scratch (in d_out). 45056 blocks x 256 threads x 8 elems.
// ---------------------------------------------------------------------------
__global__ __launch_bounds__(256)
void cvt_h(const float* __restrict__ h, _Float16* __restrict__ hf)
{
  const size_t i = ((size_t)blockIdx.x * 256 + threadIdx.x) * 8;
  f32x4 a = *(const f32x4*)&h[i];
  f32x4 b = *(const f32x4*)&h[i + 4];
  f16x8 o;
  o[0]=(_Float16)a[0]; o[1]=(_Float16)a[1]; o[2]=(_Float16)a[2]; o[3]=(_Float16)a[3];
  o[4]=(_Float16)b[0]; o[5]=(_Float16)b[1]; o[6]=(_Float16)b[2]; o[7]=(_Float16)b[3];
  *(f16x8*)&hf[i] = o;
}

// ---------------------------------------------------------------------------
// weight prep (unchanged from round 1).
// ---------------------------------------------------------------------------
__global__ __launch_bounds__(256)
void prep_w(const float* __restrict__ Wq, const float* __restrict__ Wk,
            const float* __restrict__ Wv, const float* __restrict__ Wo,
            const float* __restrict__ bq, const float* __restrict__ bk,
            const float* __restrict__ screen_d, const float* __restrict__ scale,
            _Float16* __restrict__ wcat, _Float16* __restrict__ wo16,
            _Float16* __restrict__ wvt, float* __restrict__ bcat,
            float* __restrict__ tab)
{
  const int idx = blockIdx.x * 256 + threadIdx.x;
  if (idx < 65536) {                       // Wqk -> wcat rows 0..511
    const int n = idx >> 7, c = (idx & 127) * 8;
    const float* src = (n < 256) ? &Wq[(size_t)n * 1024 + c]
                                 : &Wk[(size_t)(n - 256) * 1024 + c];
    f32x4 a = *(const f32x4*)src, b = *(const f32x4*)(src + 4);
    f16x8 o;
    o[0]=(_Float16)a[0]; o[1]=(_Float16)a[1]; o[2]=(_Float16)a[2]; o[3]=(_Float16)a[3];
    o[4]=(_Float16)b[0]; o[5]=(_Float16)b[1]; o[6]=(_Float16)b[2]; o[7]=(_Float16)b[3];
    *(f16x8*)&wcat[(size_t)n * 1024 + c] = o;
  } else if (idx < 196608) {               // Wo cvt
    const size_t e = (size_t)(idx - 65536) * 8;
    f32x4 a = *(const f32x4*)&Wo[e], b = *(const f32x4*)&Wo[e + 4];
    f16x8 o;
    o[0]=(_Float16)a[0]; o[1]=(_Float16)a[1]; o[2]=(_Float16)a[2]; o[3]=(_Float16)a[3];
    o[4]=(_Float16)b[0]; o[5]=(_Float16)b[1]; o[6]=(_Float16)b[2]; o[7]=(_Float16)b[3];
    *(f16x8*)&wo16[e] = o;
  } else if (idx < 327680) {               // WvT[n,k] = Wv[k,n]
    const int j = idx - 196608;
    const int n = j & 1023, kc = j >> 10;  // kc: 0..127
    f16x8 o;
#pragma unroll
    for (int e = 0; e < 8; ++e)
      o[e] = (_Float16)Wv[(size_t)(kc * 8 + e) * 1024 + n];
    *(f16x8*)&wvt[(size_t)n * 1024 + kc * 8] = o;
  }
  if (idx < NCAT)
    bcat[idx] = (idx < 256) ? bq[idx] : (idx < 512) ? bk[idx - 256] : 0.0f;
  if (idx < TFR * TFR) {
    const int i = idx / TFR, j = idx % TFR;
    const float r = fabsf((float)(i - j));
    float acc = 0.f, sign = 1.f;
    for (int k = 0; k < 3; ++k) {
      const float d = screen_d[k];
      acc += sign * rsqrtf(d * d + r * r + 1e-6f);
      sign = -sign;
    }
    tab[idx] = acc / (scale[0] + 1e-6f);
  }
}

// bfused[o] = sum_m Wo[o,m]*bv[m] + bo[o].  grid 1024 x 64 (one wave/row).
__global__ __launch_bounds__(64)
void bfused_k(const float* __restrict__ Wo, const float* __restrict__ bv,
              const float* __restrict__ bo, float* __restrict__ bf)
{
  const int o = blockIdx.x, l = threadIdx.x;
  float acc = 0.f;
  for (int m = l; m < 1024; m += 64) acc += Wo[(size_t)o * 1024 + m] * bv[m];
#pragma unroll
  for (int off = 32; off >= 1; off >>= 1) acc += __shfl_xor(acc, off);
  if (l == 0) bf[o] = acc + bo[o];
}

// ---------------------------------------------------------------------------
// small f16 GEMM (m97 structure) — used only for Wov = Wo @ Wv (64 blocks).
// out[m,n] = sum_k A[m,k]*B[n,k]. 128x128 tile, BK=32.
// ---------------------------------------------------------------------------
struct __align__(16) GemmSmem {
  union {
    struct { _Float16 A[128 * 32]; _Float16 B[128 * 32]; } st;
    _Float16 E16[128 * 136];
  };
};

__global__ __launch_bounds__(256)
void gemm128(const _Float16* __restrict__ A, int lda,
             const _Float16* __restrict__ B,
             _Float16* __restrict__ out, int ldo, int K)
{
  __shared__ GemmSmem sm;
  const int t  = threadIdx.x;
  const int n0 = blockIdx.x * 128;
  const int m0 = blockIdx.y * 128;
  const int w  = t >> 6, l = t & 63;
  const int wm = (w & 1) * 64, wn = (w >> 1) * 64;
  const int lr = l & 15, lg = l >> 4;

  f32x4 acc[4][4] = {};

  const int qa = t, qb = t + 256;
  const _Float16* Arow0 = A + (size_t)(m0 + (qa >> 2)) * lda + (qa & 3) * 8;
  const _Float16* Arow1 = A + (size_t)(m0 + (qb >> 2)) * lda + (qb & 3) * 8;
  const _Float16* Brow0 = B + (size_t)(n0 + (qa >> 2)) * K + (qa & 3) * 8;
  const _Float16* Brow1 = B + (size_t)(n0 + (qb >> 2)) * K + (qb & 3) * 8;
  _Float16* ldsA0 = &sm.st.A[qa * 8];
  _Float16* ldsA1 = &sm.st.A[qb * 8];
  _Float16* ldsB0 = &sm.st.B[qa * 8];
  _Float16* ldsB1 = &sm.st.B[qb * 8];

  for (int kt = 0; kt < K; kt += 32) {
    gl2lds16(Arow0 + kt, ldsA0);
    gl2lds16(Arow1 + kt, ldsA1);
    gl2lds16(Brow0 + kt, ldsB0);
    gl2lds16(Brow1 + kt, ldsB1);
    __syncthreads();
    f16x8 af[4], bf[4];
#pragma unroll
    for (int mi = 0; mi < 4; ++mi)
      af[mi] = *(const f16x8*)&sm.st.A[(wm + mi * 16 + lr) * 32 + lg * 8];
#pragma unroll
    for (int ni = 0; ni < 4; ++ni)
      bf[ni] = *(const f16x8*)&sm.st.B[(wn + ni * 16 + lr) * 32 + lg * 8];
#pragma unroll
    for (int mi = 0; mi < 4; ++mi)
#pragma unroll
      for (int ni = 0; ni < 4; ++ni)
        acc[mi][ni] = __builtin_amdgcn_mfma_f32_16x16x32_f16(af[mi], bf[ni], acc[mi][ni], 0, 0, 0);
    __syncthreads();
  }

#pragma unroll
  for (int mi = 0; mi < 4; ++mi)
#pragma unroll
    for (int ni = 0; ni < 4; ++ni) {
      const int row = wm + mi * 16 + lg * 4;
      const int col = wn + ni * 16 + lr;
#pragma unroll
      for (int r = 0; r < 4; ++r)
        sm.E16[(row + r) * 136 + col] = (_Float16)acc[mi][ni][r];
    }
  __syncthreads();
#pragma unroll
  for (int i = 0; i < 8; ++i) {
    const int q = t + i * 256;
    const int row = q >> 4, c = (q & 15) * 8;
    *(f16x8*)&out[(size_t)(m0 + row) * ldo + n0 + c] = *(const f16x8*)&sm.E16[row * 136 + c];
  }
}

// ---------------------------------------------------------------------------
// 256x256 deep-pipelined f16 GEMM (T3+T4+T5): out = A @ B^T + bias, f16 out.
// A [90112,1024] f16, B [1536,1024] f16, out [90112,1536] f16.
// 8 waves (2Mx4N), BK=64 split as 2 K-halves of 32 cols; LDS tile layout
// [buf][A/B][ks][256 rows][32 cols] f16 (64 B rows -> conflict-free b128
// fragment reads, linear global_load_lds dest). 2 phases/K-tile, 32 MFMA
// each, counted vmcnt(8) (3 half-tiles in flight), setprio around MFMA.
// Half-tile h (h = kt*4 + ks*2 + isB) staged at phase (h-6)/2, consumed at
// phase h/2; slot (h%8) freed one phase before restage (top barrier orders).
// ---------------------------------------------------------------------------
#define STAGE256(h) do {                                                     \
    const int kt2_ = (h) >> 2, isB_ = (h) & 1, ks2_ = ((h) >> 1) & 1;        \
    const int gcol_ = kt2_ * 64 + ks2_ * 32;                                 \
    _Float16* d_ = sm.S + (kt2_ & 1) * 32768 + isB_ * 16384 + ks2_ * 8192    \
                   + t * 8;                                                  \
    const _Float16* s1_ = (isB_ ? Bp1 : Ap1) + gcol_;                        \
    const _Float16* s2_ = (isB_ ? Bp2 : Ap2) + gcol_;                        \
    gl2lds16(s1_, d_);                                                       \
    gl2lds16(s2_, d_ + 4096);                                                \
  } while (0)

#define PHASE256(g, VM, ISSUE) do {                                          \
    asm volatile("s_waitcnt vmcnt(" #VM ")" ::: "memory");                   \
    __builtin_amdgcn_s_barrier();                                            \
    const int ks_ = (g) & 1, buf_ = ((g) >> 1) & 1;                          \
    const int ab_ = buf_ * 32768 + ks_ * 8192;                               \
    f16x8 af_[8], bf_[4];                                                    \
    _Pragma("unroll")                                                        \
    for (int mi = 0; mi < 8; ++mi)                                           \
      af_[mi] = *(const f16x8*)&sm.S[ab_ + (wr*128 + mi*16 + lr)*32 + lg*8]; \
    _Pragma("unroll")                                                        \
    for (int ni = 0; ni < 4; ++ni)                                           \
      bf_[ni] = *(const f16x8*)&sm.S[ab_ + 16384 + (wc*64 + ni*16 + lr)*32   \
                                     + lg*8];                                \
    if (ISSUE) { STAGE256(2*(g)+6); STAGE256(2*(g)+7); }                     \
    __builtin_amdgcn_s_setprio(1);                                           \
    _Pragma("unroll")                                                        \
    for (int mi = 0; mi < 8; ++mi)                                           \
      _Pragma("unroll")                                                      \
      for (int ni = 0; ni < 4; ++ni)                                         \
        acc[mi][ni] = __builtin_amdgcn_mfma_f32_16x16x32_f16(                \
            af_[mi], bf_[ni], acc[mi][ni], 0, 0, 0);                         \
    __builtin_amdgcn_s_setprio(0);                                           \
  } while (0)

__global__ __launch_bounds__(512, 2)
void gemm256(const _Float16* __restrict__ A,
             const _Float16* __restrict__ B,
             const float* __restrict__ bias,
             _Float16* __restrict__ out)
{
  __shared__ union {
    _Float16 S[65536];        // 128 KB staging: [2 buf][A/B][2 ks][256][32]
    _Float16 E[128 * 264];    // 67584 B epilogue
  } sm;
  const int t = threadIdx.x;
  // bijective XCD swizzle: grid (6,352) = 2112 = 8 * 264
  const int orig = blockIdx.y * 6 + blockIdx.x;
  const int wg = (orig & 7) * 264 + (orig >> 3);
  const int bx = wg % 6, by = wg / 6;
  const int n0 = bx * 256, m0 = by * 256;

  const int w  = t >> 6, l = t & 63;
  const int wr = w >> 2, wc = w & 3;     // 2 x 4 wave grid
  const int lr = l & 15, lg = l >> 4;

  // staging per-thread: row = t>>2 (0..127, +128 for 2nd load), 16B chunk t&3
  const int srow = t >> 2, cA = (t & 3) * 8;
  const _Float16* Ap1 = A + (size_t)(m0 + srow) * 1024 + cA;
  const _Float16* Ap2 = Ap1 + (size_t)128 * 1024;
  const _Float16* Bp1 = B + (size_t)(n0 + srow) * 1024 + cA;
  const _Float16* Bp2 = Bp1 + (size_t)128 * 1024;

  f32x4 acc[8][4] = {};

  // prologue: halves 0..5 (tile0 complete + tile1 ks0 A,B) = 12 loads/lane
  STAGE256(0); STAGE256(1); STAGE256(2); STAGE256(3); STAGE256(4); STAGE256(5);

  for (int g = 0; g < 29; ++g) { PHASE256(g, 8, 1); }
  PHASE256(29, 8, 0);
  PHASE256(30, 4, 0);
  PHASE256(31, 0, 0);

  __syncthreads();

  float bias4[4];
#pragma unroll
  for (int ni = 0; ni < 4; ++ni)
    bias4[ni] = bias[n0 + wc * 64 + ni * 16 + lr];

#pragma unroll
  for (int p = 0; p < 2; ++p) {          // 128-row halves
    if (wr == p) {
#pragma unroll
      for (int mi = 0; mi < 8; ++mi)
#pragma unroll
        for (int ni = 0; ni < 4; ++ni) {
          const int row = mi * 16 + lg * 4;
          const int col = wc * 64 + ni * 16 + lr;
#pragma unroll
          for (int r = 0; r < 4; ++r)
            sm.E[(row + r) * 264 + col] = (_Float16)(acc[mi][ni][r] + bias4[ni]);
        }
    }
    __syncthreads();
#pragma unroll
    for (int i = 0; i < 8; ++i) {
      const int q = t + i * 512;         // 4096 chunks: row q>>5, col (q&31)*8
      const int row = q >> 5, c = (q & 31) * 8;
      *(f16x8*)&out[(size_t)(m0 + p * 128 + row) * NCAT + n0 + c] =
          *(const f16x8*)&sm.E[row * 264 + c];
    }
    __syncthreads();
  }
}

// ---------------------------------------------------------------------------
// fold + LN: scores = Q K^T/16 + coulomb, softmax, x = P@hv + bfused + h,
// out = LN(x).  Only Q|K staged in LDS (11 KB); hv + residual go straight
// to registers (coalesced), issued before the score phases (latency hidden).
// ---------------------------------------------------------------------------
__global__ __launch_bounds__(256)
void fold_ln(const _Float16* __restrict__ qkhv, const float* __restrict__ h,
             const float* __restrict__ bfused, const float* __restrict__ tab,
             const float* __restrict__ gamma, const float* __restrict__ beta,
             float* __restrict__ out)
{
  __shared__ __align__(16) _Float16 sQK[TFR * 512];   // 11264 B
  __shared__ float sSc[TFR][12];
  __shared__ float sP[TFR][12];
  __shared__ float sRed[TFR][8];
  const int t = threadIdx.x;
  const size_t qbase = (size_t)blockIdx.x * (TFR * NCAT);
  const size_t hbase = (size_t)blockIdx.x * (TFR * HID);
  const int c = t * 4;

  // early-issue per-thread hv + residual loads (hide under score/softmax)
  f16x4 hvj[TFR];
  f32x4 hres[TFR];
#pragma unroll
  for (int j = 0; j < TFR; ++j)
    hvj[j] = *(const f16x4*)&qkhv[qbase + (size_t)j * NCAT + 512 + c];
#pragma unroll
  for (int j = 0; j < TFR; ++j)
    hres[j] = *(const f32x4*)&h[hbase + (size_t)j * HID + c];

  // stage Q|K rows (11 x 512 f16)
  for (int q = t; q < TFR * 512 / 8; q += 256) {
    const int row = q >> 6, ch = q & 63;
    *(f16x8*)&sQK[q * 8] = *(const f16x8*)&qkhv[qbase + (size_t)row * NCAT + ch * 8];
  }
  __syncthreads();

  if (t < TFR * TFR) {
    const int i = t / TFR, j = t % TFR;
    float acc = 0.f;
    for (int cc = 0; cc < DQK; cc += 8) {
      f16x8 qv = *(const f16x8*)&sQK[i * 512 + cc];
      f16x8 kv = *(const f16x8*)&sQK[j * 512 + 256 + cc];
#pragma unroll
      for (int e = 0; e < 8; ++e) acc += (float)qv[e] * (float)kv[e];
    }
    sSc[i][j] = acc * 0.0625f + tab[t];   // 1/sqrt(256)
  }
  __syncthreads();

  if (t < TFR) {
    float mx = sSc[t][0];
    for (int j = 1; j < TFR; ++j) mx = fmaxf(mx, sSc[t][j]);
    float e[TFR], sum = 0.f;
    for (int j = 0; j < TFR; ++j) { e[j] = __expf(sSc[t][j] - mx); sum += e[j]; }
    const float inv = 1.f / sum;
    for (int j = 0; j < TFR; ++j) sP[t][j] = e[j] * inv;
  }
  __syncthreads();

  const int w = t >> 6, l = t & 63;
  const f32x4 bfv = *(const f32x4*)&bfused[c];
  f32x4 acc[TFR];
#pragma unroll
  for (int i = 0; i < TFR; ++i) {
    f32x4 a = {};
#pragma unroll
    for (int j = 0; j < TFR; ++j) {
      const float p = sP[i][j];
      a[0] += p * (float)hvj[j][0]; a[1] += p * (float)hvj[j][1];
      a[2] += p * (float)hvj[j][2]; a[3] += p * (float)hvj[j][3];
    }
#pragma unroll
    for (int e = 0; e < 4; ++e) a[e] += bfv[e] + hres[i][e];
    acc[i] = a;
    float s  = a[0] + a[1] + a[2] + a[3];
    float s2 = a[0]*a[0] + a[1]*a[1] + a[2]*a[2] + a[3]*a[3];
#pragma unroll
    for (int off = 32; off >= 1; off >>= 1) {
      s  += __shfl_xor(s, off);
      s2 += __shfl_xor(s2, off);
    }
    if (l == 0) { sRed[i][w] = s; sRed[i][w + 4] = s2; }
  }
  __syncthreads();

  const f32x4 gv = *(const f32x4*)&gamma[c];
  const f32x4 bv = *(const f32x4*)&beta[c];
#pragma unroll
  for (int i = 0; i < TFR; ++i) {
    const float s  = sRed[i][0] + sRed[i][1] + sRed[i][2] + sRed[i][3];
    const float s2 = sRed[i][4] + sRed[i][5] + sRed[i][6] + sRed[i][7];
    const float mu  = s * (1.f / HID);
    const float var = s2 * (1.f / HID) - mu * mu;
    const float rs  = rsqrtf(var + 1e-5f);
    const f32x4 a = acc[i];
    f32x4 o;
#pragma unroll
    for (int e = 0; e < 4; ++e) o[e] = (a[e] - mu) * rs * gv[e] + bv[e];
    *(f32x4*)&out[hbase + (size_t)i * HID + c] = o;
  }
}

// ---------------------------------------------------------------------------
extern "C" void kernel_launch(void* const* d_in, const int* in_sizes, int n_in,
                              void* d_out, int out_size, void* d_ws, size_t ws_size,
                              hipStream_t stream)
{
  const float* h     = (const float*)d_in[0];
  const float* Wq    = (const float*)d_in[1];
  const float* bq    = (const float*)d_in[2];
  const float* Wk    = (const float*)d_in[3];
  const float* bk    = (const float*)d_in[4];
  const float* Wv    = (const float*)d_in[5];
  const float* bv    = (const float*)d_in[6];
  const float* Wo    = (const float*)d_in[7];
  const float* bo    = (const float*)d_in[8];
  const float* gamma = (const float*)d_in[9];
  const float* beta  = (const float*)d_in[10];
  const float* sd    = (const float*)d_in[11];
  const float* scal  = (const float*)d_in[12];
  float* out = (float*)d_out;

  char* w = (char*)d_ws;
  _Float16* qkhv = (_Float16*)(w + OFF_QKHV);
  _Float16* wcat = (_Float16*)(w + OFF_WCAT);
  _Float16* wvt  = (_Float16*)(w + OFF_WVT);
  _Float16* wo16 = (_Float16*)(w + OFF_WO);
  float* bcat    = (float*)(w + OFF_BCAT);
  float* bfused  = (float*)(w + OFF_BF);
  float* tab     = (float*)(w + OFF_TAB);

  // f16 copy of h parked in d_out (dead until fold_ln overwrites it)
  _Float16* hcvt = (_Float16*)d_out;

  cvt_h<<<45056, 256, 0, stream>>>(h, hcvt);
  prep_w<<<1280, 256, 0, stream>>>(Wq, Wk, Wv, Wo, bq, bk, sd, scal,
                                   wcat, wo16, wvt, bcat, tab);
  bfused_k<<<1024, 64, 0, stream>>>(Wo, bv, bo, bfused);

  // Wov = Wo @ Wv -> wcat rows 512..1535
  gemm128<<<dim3(8, 8), 256, 0, stream>>>(
      wo16, 1024, wvt, wcat + (size_t)512 * 1024, 1024, 1024);

  // qkhv = h16 @ [Wqk ; Wov]^T + [bqk ; 0]
  gemm256<<<dim3(6, 352), 512, 0, stream>>>(hcvt, wcat, bcat, qkhv);

  // scores/softmax/PV + bfused + residual + LayerNorm
  fold_ln<<<NBATCH, 256, 0, stream>>>(qkhv, h, bfused, tab, gamma, beta, out);
}